// Round 5
// baseline (1289.439 us; speedup 1.0000x reference)
//
#include <hip/hip_runtime.h>
#include <math.h>

#define N_NODES 100000
#define N_EDGES 1600000
#define F_IN    512
#define HID     128
#define NCLS    64
#define NLAYERS 8
#define NT      (N_NODES / 16)            // 6250 exact row-tiles of 16
#define NSCANB  ((N_NODES + 255) / 256)   // 391
#define NBLK    (N_NODES / 32)            // 3125 exact 32-node blocks

typedef __attribute__((ext_vector_type(8))) short short8;
typedef __attribute__((ext_vector_type(4))) float float4v;

// XOR swizzle for the A-fragment LDS region: brings the fragment-q bits (8..9)
// into bank bits (4..5). Involution; applied on both write and read.
#define SWZB(b) ((b) ^ ((((b) >> 8) & 3) << 4))

// ---- bf16 helpers (round-to-nearest-even) ----
__device__ inline unsigned short f2bf(float f) {
    unsigned int u = __float_as_uint(f);
    unsigned int r = u + 0x7fffu + ((u >> 16) & 1u);
    return (unsigned short)(r >> 16);
}
__device__ inline float bf2f(unsigned short h) {
    return __uint_as_float(((unsigned int)h) << 16);
}
__device__ inline uint4 pack8(const unsigned short* v) {
    uint4 u;
    u.x = (unsigned)v[0] | ((unsigned)v[1] << 16);
    u.y = (unsigned)v[2] | ((unsigned)v[3] << 16);
    u.z = (unsigned)v[4] | ((unsigned)v[5] << 16);
    u.w = (unsigned)v[6] | ((unsigned)v[7] << 16);
    return u;
}
// accumulate 8 bf16 (packed uint4, low/high order) * v into a[8]
__device__ inline void bf8_fma(float* a, uint4 u, float v) {
    a[0] += v * __uint_as_float(u.x << 16);
    a[1] += v * __uint_as_float(u.x & 0xffff0000u);
    a[2] += v * __uint_as_float(u.y << 16);
    a[3] += v * __uint_as_float(u.y & 0xffff0000u);
    a[4] += v * __uint_as_float(u.z << 16);
    a[5] += v * __uint_as_float(u.z & 0xffff0000u);
    a[6] += v * __uint_as_float(u.w << 16);
    a[7] += v * __uint_as_float(u.w & 0xffff0000u);
}
__device__ inline void unpack8(float* f, uint4 u) {
    f[0] = __uint_as_float(u.x << 16); f[1] = __uint_as_float(u.x & 0xffff0000u);
    f[2] = __uint_as_float(u.y << 16); f[3] = __uint_as_float(u.y & 0xffff0000u);
    f[4] = __uint_as_float(u.z << 16); f[5] = __uint_as_float(u.z & 0xffff0000u);
    f[6] = __uint_as_float(u.w << 16); f[7] = __uint_as_float(u.w & 0xffff0000u);
}
// split fp32 into hi/lo bf16 and store into vector element j of ahi/alo
__device__ inline void split_into(short8& ahi, short8& alo, int j, float f) {
    unsigned short h = f2bf(f);
    ahi[j] = (short)h;
    alo[j] = (short)f2bf(f - bf2f(h));
}

// ================= CSR build =================

__global__ __launch_bounds__(256) void cnt_init(int* __restrict__ cnt) {
    int i = blockIdx.x * 256 + threadIdx.x;
    if (i < N_NODES) cnt[i] = 0;
}
__global__ __launch_bounds__(256) void cnt_count(const int* __restrict__ dst,
                                                 int* __restrict__ cnt) {
    int e = blockIdx.x * 256 + threadIdx.x;
    if (e < N_EDGES) atomicAdd(&cnt[dst[e]], 1);
}
__global__ __launch_bounds__(256) void make_dinv(const int* __restrict__ cnt,
                                                 float* __restrict__ dinv) {
    int i = blockIdx.x * 256 + threadIdx.x;
    if (i < N_NODES) dinv[i] = rsqrtf((float)(cnt[i] + 1));
}
__global__ __launch_bounds__(256) void scan_block(const int* __restrict__ cnt,
                                                  int* __restrict__ partial,
                                                  int* __restrict__ bsum) {
    __shared__ int tmp[256];
    int t = threadIdx.x, i = blockIdx.x * 256 + t;
    int v = (i < N_NODES) ? cnt[i] : 0;
    tmp[t] = v;
    __syncthreads();
#pragma unroll
    for (int off = 1; off < 256; off <<= 1) {
        int add = (t >= off) ? tmp[t - off] : 0;
        __syncthreads();
        tmp[t] += add;
        __syncthreads();
    }
    if (i < N_NODES) partial[i] = tmp[t];
    if (t == 255) bsum[blockIdx.x] = tmp[255];
}
__global__ void scan_bsum(int* __restrict__ bsum) {
    if (threadIdx.x == 0 && blockIdx.x == 0) {
        int acc = 0;
        for (int i = 0; i < NSCANB; i++) { int v = bsum[i]; bsum[i] = acc; acc += v; }
    }
}
__global__ __launch_bounds__(256) void finalize_rowptr(const int* __restrict__ cnt,
                                                       const int* __restrict__ partial,
                                                       const int* __restrict__ bsum,
                                                       int* __restrict__ row_ptr,
                                                       int* __restrict__ cursor) {
    int i = blockIdx.x * 256 + threadIdx.x;
    if (i < N_NODES) {
        int ex = partial[i] - cnt[i] + bsum[blockIdx.x];
        row_ptr[i] = ex;
        cursor[i]  = ex;
        if (i == N_NODES - 1) row_ptr[N_NODES] = ex + cnt[i];
    }
}
__global__ __launch_bounds__(256) void scatter_edges(const int* __restrict__ srcI,
                                                     const int* __restrict__ dstI,
                                                     const float* __restrict__ dinv,
                                                     int* __restrict__ cursor,
                                                     int2* __restrict__ rec) {
    int e = blockIdx.x * 256 + threadIdx.x;
    if (e < N_EDGES) {
        int s = srcI[e], d = dstI[e];
        int pos = atomicAdd(&cursor[d], 1);
        rec[pos] = make_int2(s, __float_as_int(dinv[s] * dinv[d]));
    }
}

// ================= weight pre-conversion =================
// Layout: chunk-major. wip chunk c (c=0..15) = 16 KB contiguous: 8 nt-frags of
// 1024 ushorts each (hi at [0,512), lo at [512,1024)), frag elem = lane*8+j.
__global__ __launch_bounds__(64) void conv_win(const float* __restrict__ w,
                                               unsigned short* __restrict__ wip) {
    int nt = blockIdx.x >> 4;
    int c  = blockIdx.x & 15;
    int lane = threadIdx.x;
    int n  = nt * 16 + (lane & 15);
    int kb = c * 32 + (lane >> 4) * 8;
    unsigned short hi[8], lo[8];
#pragma unroll
    for (int j = 0; j < 8; j++) {
        float v = w[(size_t)(kb + j) * HID + n];
        hi[j] = f2bf(v);
        lo[j] = f2bf(v - bf2f(hi[j]));
    }
    size_t base = ((size_t)c * 8 + nt) * 1024 + (size_t)lane * 8;
    *(uint4*)&wip[base]       = pack8(hi);
    *(uint4*)&wip[base + 512] = pack8(lo);
}

// W'_l = beta_l * conv_w[l] + (1-beta_l) * I ; chunk-major per layer (c=0..3)
__global__ __launch_bounds__(64) void conv_wl(const float* __restrict__ cw,
                                              unsigned short* __restrict__ wlp) {
    int l  = blockIdx.x >> 5;
    int nt = (blockIdx.x >> 2) & 7;
    int c  = blockIdx.x & 3;
    int lane = threadIdx.x;
    float beta = logf(0.5f / (float)(l + 1) + 1.0f);
    int n  = nt * 16 + (lane & 15);
    int kb = c * 32 + (lane >> 4) * 8;
    const float* W = cw + (size_t)l * HID * HID;
    unsigned short hi[8], lo[8];
#pragma unroll
    for (int j = 0; j < 8; j++) {
        int k = kb + j;
        float v = beta * W[(size_t)k * HID + n] + ((k == n) ? (1.0f - beta) : 0.0f);
        hi[j] = f2bf(v);
        lo[j] = f2bf(v - bf2f(hi[j]));
    }
    size_t base = (size_t)l * 32768 + ((size_t)c * 8 + nt) * 1024 + (size_t)lane * 8;
    *(uint4*)&wlp[base]       = pack8(hi);
    *(uint4*)&wlp[base + 512] = pack8(lo);
}

// w_out [128][64] -> B-frags hi/lo per (nt 0..3, c 0..3) (local layout, unstaged)
__global__ __launch_bounds__(64) void conv_wout(const float* __restrict__ w,
                                                unsigned short* __restrict__ wop) {
    int nt = blockIdx.x >> 2;
    int c  = blockIdx.x & 3;
    int lane = threadIdx.x;
    int n  = nt * 16 + (lane & 15);
    int kb = c * 32 + (lane >> 4) * 8;
    unsigned short hi[8], lo[8];
#pragma unroll
    for (int j = 0; j < 8; j++) {
        float v = w[(size_t)(kb + j) * NCLS + n];
        hi[j] = f2bf(v);
        lo[j] = f2bf(v - bf2f(hi[j]));
    }
    size_t base = ((size_t)nt * 4 + c) * 1024 + (size_t)lane * 8;
    *(uint4*)&wop[base]       = pack8(hi);
    *(uint4*)&wop[base + 512] = pack8(lo);
}

// ================= input GEMM: h = x @ w_in + b (LDS-staged weights) =================
__global__ __launch_bounds__(256) void in_gemm_mfma(const float* __restrict__ x,
        const unsigned short* __restrict__ wip, const float* __restrict__ bias,
        unsigned short* __restrict__ hb, unsigned short* __restrict__ h0b) {
    __shared__ unsigned short wlds[8192];      // 16 KB: one K-chunk of B-frags
    __shared__ unsigned short tile[64][136];   // 17 KB output staging
    int tid = threadIdx.x;
    int wave = tid >> 6, lane = tid & 63;
    int t = blockIdx.x * 4 + wave;
    int m = lane & 15, q = lane >> 4;
    int tc = (t < NT) ? t : (NT - 1);          // clamp for address safety

    const uint4* wg = (const uint4*)wip;       // chunk c at uint4 index c*1024
    uint4 pf0 = wg[tid];
    uint4 pf1 = wg[tid + 256];
    uint4 pf2 = wg[tid + 512];
    uint4 pf3 = wg[tid + 768];

    float4v acc[8];
#pragma unroll
    for (int nt = 0; nt < 8; nt++) acc[nt] = (float4v){0.f, 0.f, 0.f, 0.f};
    const float* xr = x + (size_t)(tc * 16 + m) * F_IN + q * 8;
    uint4* wl4 = (uint4*)wlds;

    for (int c = 0; c < 16; c++) {
        wl4[tid] = pf0; wl4[tid + 256] = pf1; wl4[tid + 512] = pf2; wl4[tid + 768] = pf3;
        __syncthreads();
        if (c < 15) {
            const uint4* wn = wg + (size_t)(c + 1) * 1024;
            pf0 = wn[tid]; pf1 = wn[tid + 256]; pf2 = wn[tid + 512]; pf3 = wn[tid + 768];
        }
        float4 x0 = *(const float4*)(xr + c * 32);
        float4 x1 = *(const float4*)(xr + c * 32 + 4);
        short8 ahi, alo;
        split_into(ahi, alo, 0, x0.x); split_into(ahi, alo, 1, x0.y);
        split_into(ahi, alo, 2, x0.z); split_into(ahi, alo, 3, x0.w);
        split_into(ahi, alo, 4, x1.x); split_into(ahi, alo, 5, x1.y);
        split_into(ahi, alo, 6, x1.z); split_into(ahi, alo, 7, x1.w);
#pragma unroll
        for (int nt = 0; nt < 8; nt++) {
            short8 bhi = *(short8*)&wlds[nt * 1024 + lane * 8];
            short8 blo = *(short8*)&wlds[nt * 1024 + 512 + lane * 8];
            acc[nt] = __builtin_amdgcn_mfma_f32_16x16x32_bf16(ahi, bhi, acc[nt], 0, 0, 0);
            acc[nt] = __builtin_amdgcn_mfma_f32_16x16x32_bf16(ahi, blo, acc[nt], 0, 0, 0);
            acc[nt] = __builtin_amdgcn_mfma_f32_16x16x32_bf16(alo, bhi, acc[nt], 0, 0, 0);
        }
        __syncthreads();
    }

    if (t < NT) {
#pragma unroll
        for (int nt = 0; nt < 8; nt++) {
            float bb = bias[nt * 16 + m];
#pragma unroll
            for (int r = 0; r < 4; r++)
                tile[wave * 16 + q * 4 + r][nt * 16 + m] = f2bf(acc[nt][r] + bb);
        }
    }
    __syncthreads();

    int nl = tid >> 2, part = tid & 3;
    int node = blockIdx.x * 64 + nl;
    if (node < N_NODES) {
        uint4* d1 = (uint4*)&hb [(size_t)node * HID + part * 32];
        uint4* d2 = (uint4*)&h0b[(size_t)node * HID + part * 32];
#pragma unroll
        for (int j = 0; j < 4; j++) {
            uint4 u = *(uint4*)&tile[nl][part * 32 + j * 8];
            d1[j] = u; d2[j] = u;
        }
    }
}

// ================= fused SpMM + residual mix + layer GEMM =================
// Block = 32 nodes (2 waves, 16 KB LDS -> 10 blocks/CU, 20 waves/CU).
// Phase 1: one node per 16-lane quarter; aggregate in registers with 8-deep
// batching, residual-mix, write MFMA A-frags into swizzled per-wave LDS.
// Phase 2: per-wave GEMM h_out = elu(s @ W'_l), A from LDS, B from global.
// Epilogue: per-wave LDS transpose staging (reuses A-frag region).
// Grid is exact (32*3125 = 100000): no bounds checks needed.
template <int LAST>
__global__ __launch_bounds__(128, 5) void spmm_gemm(const int* __restrict__ row_ptr,
        const int2* __restrict__ rec, const float* __restrict__ dinv,
        const unsigned short* __restrict__ hin, const unsigned short* __restrict__ h0b,
        const unsigned short* __restrict__ wlp, void* __restrict__ outp) {
    __shared__ __align__(16) unsigned short afr[8192];   // 16 KB: 2 waves x 8 KB
    int tid = threadIdx.x;
    int wave = tid >> 6, lane = tid & 63;
    int qu = lane >> 4, fl = lane & 15;
    char* af = (char*)afr;

    // ---- phase 1: aggregation, 4 rounds of (node per quarter) ----
    int base = blockIdx.x * 32 + wave * 16;
#pragma unroll 1
    for (int g = 0; g < 4; ++g) {
        int nc = base + g * 4 + qu;
        int e0 = row_ptr[nc], e1 = row_ptr[nc + 1];
        // issue self/residual loads early (overlap with gather)
        float dd = dinv[nc];
        uint4 hv = *(const uint4*)(hin + (size_t)nc * HID + fl * 8);
        uint4 zv = *(const uint4*)(h0b + (size_t)nc * HID + fl * 8);
        float a[8] = {0.f, 0.f, 0.f, 0.f, 0.f, 0.f, 0.f, 0.f};
        int e = e0;
        for (; e + 7 < e1; e += 8) {
            int2 r0 = rec[e],     r1 = rec[e + 1], r2 = rec[e + 2], r3 = rec[e + 3];
            int2 r4 = rec[e + 4], r5 = rec[e + 5], r6 = rec[e + 6], r7 = rec[e + 7];
            uint4 u0 = *(const uint4*)(hin + (size_t)r0.x * HID + fl * 8);
            uint4 u1 = *(const uint4*)(hin + (size_t)r1.x * HID + fl * 8);
            uint4 u2 = *(const uint4*)(hin + (size_t)r2.x * HID + fl * 8);
            uint4 u3 = *(const uint4*)(hin + (size_t)r3.x * HID + fl * 8);
            uint4 u4 = *(const uint4*)(hin + (size_t)r4.x * HID + fl * 8);
            uint4 u5 = *(const uint4*)(hin + (size_t)r5.x * HID + fl * 8);
            uint4 u6 = *(const uint4*)(hin + (size_t)r6.x * HID + fl * 8);
            uint4 u7 = *(const uint4*)(hin + (size_t)r7.x * HID + fl * 8);
            bf8_fma(a, u0, __int_as_float(r0.y));
            bf8_fma(a, u1, __int_as_float(r1.y));
            bf8_fma(a, u2, __int_as_float(r2.y));
            bf8_fma(a, u3, __int_as_float(r3.y));
            bf8_fma(a, u4, __int_as_float(r4.y));
            bf8_fma(a, u5, __int_as_float(r5.y));
            bf8_fma(a, u6, __int_as_float(r6.y));
            bf8_fma(a, u7, __int_as_float(r7.y));
        }
        for (; e + 3 < e1; e += 4) {
            int2 r0 = rec[e], r1 = rec[e + 1], r2 = rec[e + 2], r3 = rec[e + 3];
            uint4 u0 = *(const uint4*)(hin + (size_t)r0.x * HID + fl * 8);
            uint4 u1 = *(const uint4*)(hin + (size_t)r1.x * HID + fl * 8);
            uint4 u2 = *(const uint4*)(hin + (size_t)r2.x * HID + fl * 8);
            uint4 u3 = *(const uint4*)(hin + (size_t)r3.x * HID + fl * 8);
            bf8_fma(a, u0, __int_as_float(r0.y));
            bf8_fma(a, u1, __int_as_float(r1.y));
            bf8_fma(a, u2, __int_as_float(r2.y));
            bf8_fma(a, u3, __int_as_float(r3.y));
        }
        for (; e < e1; ++e) {
            int2 r0 = rec[e];
            uint4 u0 = *(const uint4*)(hin + (size_t)r0.x * HID + fl * 8);
            bf8_fma(a, u0, __int_as_float(r0.y));
        }
        // self-loop + initial-residual mix
        float d2 = dd * dd;
        float hvf[8], zvf[8];
        unpack8(hvf, hv);
        unpack8(zvf, zv);
        short8 ohi, olo;
#pragma unroll
        for (int j = 0; j < 8; ++j) {
            float o = 0.9f * (a[j] + d2 * hvf[j]) + 0.1f * zvf[j];
            split_into(ohi, olo, j, o);
        }
        // A-frag layout: byte = wave*8192 + c*2048 + sel*1024 + q*256 + m*16
        // writer: c = fl>>2, q = fl&3, m = row within wave tile
        int mrow = g * 4 + qu;
        int b0 = wave * 8192 + (fl >> 2) * 2048 + (fl & 3) * 256 + mrow * 16;
        *(short8*)(af + SWZB(b0)) = ohi;
        *(short8*)(af + SWZB(b0 + 1024)) = olo;
    }
    __syncthreads();   // A-frags visible (2-wave barrier, cheap)

    // ---- phase 2: per-wave GEMM, A from LDS, B from global ----
    float4v acc[8];
#pragma unroll
    for (int nt = 0; nt < 8; ++nt) acc[nt] = (float4v){0.f, 0.f, 0.f, 0.f};
    const short8* wp8 = (const short8*)wlp;
#pragma unroll
    for (int c = 0; c < 4; ++c) {
        int rb = wave * 8192 + c * 2048 + lane * 16;
        short8 ahi = *(const short8*)(af + SWZB(rb));
        short8 alo = *(const short8*)(af + SWZB(rb + 1024));
#pragma unroll
        for (int nt = 0; nt < 8; ++nt) {
            short8 bhi = wp8[(size_t)(c * 8 + nt) * 128 + lane];
            short8 blo = wp8[(size_t)(c * 8 + nt) * 128 + 64 + lane];
            acc[nt] = __builtin_amdgcn_mfma_f32_16x16x32_bf16(ahi, bhi, acc[nt], 0, 0, 0);
            acc[nt] = __builtin_amdgcn_mfma_f32_16x16x32_bf16(ahi, blo, acc[nt], 0, 0, 0);
            acc[nt] = __builtin_amdgcn_mfma_f32_16x16x32_bf16(alo, bhi, acc[nt], 0, 0, 0);
        }
    }

    if (LAST) {
        // write f32 h for the out GEMM (t exact: blockIdx*2+wave < NT)
        int t = blockIdx.x * 2 + wave;
        float* hf = (float*)outp;
#pragma unroll
        for (int nt = 0; nt < 8; ++nt) {
#pragma unroll
            for (int r = 0; r < 4; ++r) {
                float v = acc[nt][r];
                v = (v > 0.f) ? v : (expf(v) - 1.0f);
                hf[(size_t)(t * 16 + qu * 4 + r) * HID + nt * 16 + fl] = v;
            }
        }
    } else {
        __syncthreads();   // A-frag reads done; reuse per-wave region as out tile
        unsigned short* tw = (unsigned short*)(af + wave * 8192);  // [16][136]
#pragma unroll
        for (int nt = 0; nt < 8; ++nt) {
#pragma unroll
            for (int r = 0; r < 4; ++r) {
                float v = acc[nt][r];
                v = (v > 0.f) ? v : (expf(v) - 1.0f);
                tw[(qu * 4 + r) * 136 + nt * 16 + fl] = f2bf(v);
            }
        }
        __syncthreads();
        unsigned short* hout = (unsigned short*)outp;
        int nl2 = lane >> 2, part = lane & 3;
        int node = blockIdx.x * 32 + wave * 16 + nl2;
        uint4* d1 = (uint4*)&hout[(size_t)node * HID + part * 32];
#pragma unroll
        for (int j = 0; j < 4; ++j) d1[j] = *(uint4*)&tw[nl2 * 136 + part * 32 + j * 8];
    }
}

// ================= out GEMM + log_softmax (split-bf16 MFMA) =================
__global__ __launch_bounds__(256) void out_gemm(const float* __restrict__ hf,
        const unsigned short* __restrict__ wop, const float* __restrict__ bias,
        float* __restrict__ out) {
    int wave = threadIdx.x >> 6;
    int lane = threadIdx.x & 63;
    int t = blockIdx.x * 4 + wave;
    int m = lane & 15, q = lane >> 4;
    if (t >= NT) return;

    float4v acc[4];
#pragma unroll
    for (int nt = 0; nt < 4; nt++) acc[nt] = (float4v){0.f, 0.f, 0.f, 0.f};
    const float* hr = hf + (size_t)(t * 16 + m) * HID + q * 8;
    const short8* wp8 = (const short8*)wop;
#pragma unroll
    for (int c = 0; c < 4; c++) {
        float4 x0 = *(const float4*)(hr + c * 32);
        float4 x1 = *(const float4*)(hr + c * 32 + 4);
        short8 ahi, alo;
        split_into(ahi, alo, 0, x0.x); split_into(ahi, alo, 1, x0.y);
        split_into(ahi, alo, 2, x0.z); split_into(ahi, alo, 3, x0.w);
        split_into(ahi, alo, 4, x1.x); split_into(ahi, alo, 5, x1.y);
        split_into(ahi, alo, 6, x1.z); split_into(ahi, alo, 7, x1.w);
#pragma unroll
        for (int nt = 0; nt < 4; nt++) {
            short8 bhi = wp8[(size_t)(nt * 4 + c) * 128 + lane];
            short8 blo = wp8[(size_t)(nt * 4 + c) * 128 + 64 + lane];
            acc[nt] = __builtin_amdgcn_mfma_f32_16x16x32_bf16(ahi, bhi, acc[nt], 0, 0, 0);
            acc[nt] = __builtin_amdgcn_mfma_f32_16x16x32_bf16(ahi, blo, acc[nt], 0, 0, 0);
            acc[nt] = __builtin_amdgcn_mfma_f32_16x16x32_bf16(alo, bhi, acc[nt], 0, 0, 0);
        }
    }
    float bn[4];
#pragma unroll
    for (int nt = 0; nt < 4; nt++) bn[nt] = bias[nt * 16 + m];
#pragma unroll
    for (int r = 0; r < 4; r++) {
        float v0 = acc[0][r] + bn[0], v1 = acc[1][r] + bn[1];
        float v2 = acc[2][r] + bn[2], v3 = acc[3][r] + bn[3];
        float mx = fmaxf(fmaxf(v0, v1), fmaxf(v2, v3));
#pragma unroll
        for (int msk = 1; msk < 16; msk <<= 1) mx = fmaxf(mx, __shfl_xor(mx, msk));
        float ssum = expf(v0 - mx) + expf(v1 - mx) + expf(v2 - mx) + expf(v3 - mx);
#pragma unroll
        for (int msk = 1; msk < 16; msk <<= 1) ssum += __shfl_xor(ssum, msk);
        float lg = mx + logf(ssum);
        size_t base = (size_t)(t * 16 + q * 4 + r) * NCLS + m;
        out[base]      = v0 - lg;
        out[base + 16] = v1 - lg;
        out[base + 32] = v2 - lg;
        out[base + 48] = v3 - lg;
    }
}

// ================= launch =================

extern "C" void kernel_launch(void* const* d_in, const int* in_sizes, int n_in,
                              void* d_out, int out_size, void* d_ws, size_t ws_size,
                              hipStream_t stream) {
    const float* x      = (const float*)d_in[0];
    const int*   ei     = (const int*)  d_in[1];
    const float* w_in   = (const float*)d_in[2];
    const float* b_in   = (const float*)d_in[3];
    const float* conv_w = (const float*)d_in[4];
    const float* w_out  = (const float*)d_in[5];
    const float* b_out  = (const float*)d_in[6];
    float* out = (float*)d_out;

    const int* srcI = ei;
    const int* dstI = ei + N_EDGES;

    char* ws = (char*)d_ws;
    float* dinv    = (float*)(ws + 0x000000);
    int*   cnt     = (int*)  (ws + 0x080000);
    int*   partial = (int*)  (ws + 0x100000);
    int*   bsum    = (int*)  (ws + 0x180000);
    int*   row_ptr = (int*)  (ws + 0x190000);
    int*   cursor  = (int*)  (ws + 0x200000);
    int2*  rec     = (int2*) (ws + 0x280000);                  // 12.8 MB
    unsigned short* wip = (unsigned short*)(ws + 0xF00000);    // 256 KB
    unsigned short* wlp = (unsigned short*)(ws + 0xF40000);    // 512 KB
    unsigned short* wop = (unsigned short*)(ws + 0xFC0000);    // 32 KB
    unsigned short* hb  = (unsigned short*)(ws + 0x1000000);   // 25.6 MB
    unsigned short* h0b = hb + (size_t)N_NODES * HID;          // 25.6 MB
    unsigned short* hb2 = h0b + (size_t)N_NODES * HID;         // 25.6 MB (ping-pong)
    float* hf = (float*)(hb2 + 2 * (size_t)N_NODES * HID);     // 51.2 MB

    int gN = (N_NODES + 255) / 256;
    int gE = (N_EDGES + 255) / 256;
    int gT = (NT + 3) / 4;                                     // 1563

    cnt_init<<<gN, 256, 0, stream>>>(cnt);
    cnt_count<<<gE, 256, 0, stream>>>(dstI, cnt);
    make_dinv<<<gN, 256, 0, stream>>>(cnt, dinv);
    scan_block<<<NSCANB, 256, 0, stream>>>(cnt, partial, bsum);
    scan_bsum<<<1, 64, 0, stream>>>(bsum);
    finalize_rowptr<<<NSCANB, 256, 0, stream>>>(cnt, partial, bsum, row_ptr, cursor);
    scatter_edges<<<gE, 256, 0, stream>>>(srcI, dstI, dinv, cursor, rec);

    conv_win<<<128, 64, 0, stream>>>(w_in, wip);
    conv_wl<<<256, 64, 0, stream>>>(conv_w, wlp);
    conv_wout<<<16, 64, 0, stream>>>(w_out, wop);

    in_gemm_mfma<<<gT, 256, 0, stream>>>(x, wip, b_in, hb, h0b);

    unsigned short* cur = hb;
    unsigned short* nxt = hb2;
    for (int l = 0; l < NLAYERS; l++) {
        const unsigned short* wl = wlp + (size_t)l * 32768;
        if (l < NLAYERS - 1) {
            spmm_gemm<0><<<NBLK, 128, 0, stream>>>(row_ptr, rec, dinv, cur, h0b, wl, nxt);
            unsigned short* t = cur; cur = nxt; nxt = t;
        } else {
            spmm_gemm<1><<<NBLK, 128, 0, stream>>>(row_ptr, rec, dinv, cur, h0b, wl, hf);
        }
    }

    out_gemm<<<gT, 256, 0, stream>>>(hf, wop, b_out, out);
}

// Round 6
// 1189.213 us; speedup vs baseline: 1.0843x; 1.0843x over previous
//
#include <hip/hip_runtime.h>
#include <math.h>

#define N_NODES 100000
#define N_EDGES 1600000
#define F_IN    512
#define HID     128
#define NCLS    64
#define NLAYERS 8
#define NT      (N_NODES / 16)            // 6250 exact row-tiles of 16
#define NSCANB  ((N_NODES + 255) / 256)   // 391

typedef __attribute__((ext_vector_type(8))) short short8;
typedef __attribute__((ext_vector_type(4))) float float4v;

// XOR swizzle for the A-fragment LDS region: brings the fragment-q bits (8..9)
// into bank bits (4..5). Involution; applied on both write and read.
#define SWZB(b) ((b) ^ ((((b) >> 8) & 3) << 4))
// XOR swizzle for row-major [16][128] bf16 planes (row stride 256 B): fold
// row&7 into bank bits 4..6. Involution; applied on both write and read.
#define SWZC(b) ((b) ^ ((((b) >> 8) & 7) << 4))

// ---- bf16 helpers (round-to-nearest-even) ----
__device__ inline unsigned short f2bf(float f) {
    unsigned int u = __float_as_uint(f);
    unsigned int r = u + 0x7fffu + ((u >> 16) & 1u);
    return (unsigned short)(r >> 16);
}
__device__ inline float bf2f(unsigned short h) {
    return __uint_as_float(((unsigned int)h) << 16);
}
__device__ inline uint4 pack8(const unsigned short* v) {
    uint4 u;
    u.x = (unsigned)v[0] | ((unsigned)v[1] << 16);
    u.y = (unsigned)v[2] | ((unsigned)v[3] << 16);
    u.z = (unsigned)v[4] | ((unsigned)v[5] << 16);
    u.w = (unsigned)v[6] | ((unsigned)v[7] << 16);
    return u;
}
// accumulate 8 bf16 (packed uint4, low/high order) * v into a[8]
__device__ inline void bf8_fma(float* a, uint4 u, float v) {
    a[0] += v * __uint_as_float(u.x << 16);
    a[1] += v * __uint_as_float(u.x & 0xffff0000u);
    a[2] += v * __uint_as_float(u.y << 16);
    a[3] += v * __uint_as_float(u.y & 0xffff0000u);
    a[4] += v * __uint_as_float(u.z << 16);
    a[5] += v * __uint_as_float(u.z & 0xffff0000u);
    a[6] += v * __uint_as_float(u.w << 16);
    a[7] += v * __uint_as_float(u.w & 0xffff0000u);
}
__device__ inline void unpack8(float* f, uint4 u) {
    f[0] = __uint_as_float(u.x << 16); f[1] = __uint_as_float(u.x & 0xffff0000u);
    f[2] = __uint_as_float(u.y << 16); f[3] = __uint_as_float(u.y & 0xffff0000u);
    f[4] = __uint_as_float(u.z << 16); f[5] = __uint_as_float(u.z & 0xffff0000u);
    f[6] = __uint_as_float(u.w << 16); f[7] = __uint_as_float(u.w & 0xffff0000u);
}
// split fp32 into hi/lo bf16 and store into vector element j of ahi/alo
__device__ inline void split_into(short8& ahi, short8& alo, int j, float f) {
    unsigned short h = f2bf(f);
    ahi[j] = (short)h;
    alo[j] = (short)f2bf(f - bf2f(h));
}

// ================= CSR build =================

__global__ __launch_bounds__(256) void cnt_init(int* __restrict__ cnt) {
    int i = blockIdx.x * 256 + threadIdx.x;
    if (i < N_NODES) cnt[i] = 0;
}
__global__ __launch_bounds__(256) void cnt_count(const int* __restrict__ dst,
                                                 int* __restrict__ cnt) {
    int e = blockIdx.x * 256 + threadIdx.x;
    if (e < N_EDGES) atomicAdd(&cnt[dst[e]], 1);
}
__global__ __launch_bounds__(256) void make_dinv(const int* __restrict__ cnt,
                                                 float* __restrict__ dinv) {
    int i = blockIdx.x * 256 + threadIdx.x;
    if (i < N_NODES) dinv[i] = rsqrtf((float)(cnt[i] + 1));
}
__global__ __launch_bounds__(256) void scan_block(const int* __restrict__ cnt,
                                                  int* __restrict__ partial,
                                                  int* __restrict__ bsum) {
    __shared__ int tmp[256];
    int t = threadIdx.x, i = blockIdx.x * 256 + t;
    int v = (i < N_NODES) ? cnt[i] : 0;
    tmp[t] = v;
    __syncthreads();
#pragma unroll
    for (int off = 1; off < 256; off <<= 1) {
        int add = (t >= off) ? tmp[t - off] : 0;
        __syncthreads();
        tmp[t] += add;
        __syncthreads();
    }
    if (i < N_NODES) partial[i] = tmp[t];
    if (t == 255) bsum[blockIdx.x] = tmp[255];
}
// parallel exclusive scan of bsum[NSCANB] in one 256-thread block (2 elem/thread)
__global__ __launch_bounds__(256) void scan_b2(int* __restrict__ b) {
    __shared__ int ps[256];
    int t = threadIdx.x;
    int i0 = 2 * t, i1 = 2 * t + 1;
    int v0 = (i0 < NSCANB) ? b[i0] : 0;
    int v1 = (i1 < NSCANB) ? b[i1] : 0;
    int s = v0 + v1;
    ps[t] = s;
    __syncthreads();
#pragma unroll
    for (int off = 1; off < 256; off <<= 1) {
        int add = (t >= off) ? ps[t - off] : 0;
        __syncthreads();
        ps[t] += add;
        __syncthreads();
    }
    int excl = ps[t] - s;
    if (i0 < NSCANB) b[i0] = excl;
    if (i1 < NSCANB) b[i1] = excl + v0;
}
__global__ __launch_bounds__(256) void finalize_rowptr(const int* __restrict__ cnt,
                                                       const int* __restrict__ partial,
                                                       const int* __restrict__ bsum,
                                                       int* __restrict__ row_ptr,
                                                       int* __restrict__ cursor) {
    int i = blockIdx.x * 256 + threadIdx.x;
    if (i < N_NODES) {
        int ex = partial[i] - cnt[i] + bsum[blockIdx.x];
        row_ptr[i] = ex;
        cursor[i]  = ex;
        if (i == N_NODES - 1) row_ptr[N_NODES] = ex + cnt[i];
    }
}
__global__ __launch_bounds__(256) void scatter_edges(const int* __restrict__ srcI,
                                                     const int* __restrict__ dstI,
                                                     const float* __restrict__ dinv,
                                                     int* __restrict__ cursor,
                                                     int2* __restrict__ rec) {
    int e = blockIdx.x * 256 + threadIdx.x;
    if (e < N_EDGES) {
        int s = srcI[e], d = dstI[e];
        int pos = atomicAdd(&cursor[d], 1);
        rec[pos] = make_int2(s, __float_as_int(dinv[s] * dinv[d]));
    }
}

// ================= weight pre-conversion =================
// Layout: chunk-major. wip chunk c (c=0..15) = 16 KB contiguous: 8 nt-frags of
// 1024 ushorts each (hi at [0,512), lo at [512,1024)), frag elem = lane*8+j.
__global__ __launch_bounds__(64) void conv_win(const float* __restrict__ w,
                                               unsigned short* __restrict__ wip) {
    int nt = blockIdx.x >> 4;
    int c  = blockIdx.x & 15;
    int lane = threadIdx.x;
    int n  = nt * 16 + (lane & 15);
    int kb = c * 32 + (lane >> 4) * 8;
    unsigned short hi[8], lo[8];
#pragma unroll
    for (int j = 0; j < 8; j++) {
        float v = w[(size_t)(kb + j) * HID + n];
        hi[j] = f2bf(v);
        lo[j] = f2bf(v - bf2f(hi[j]));
    }
    size_t base = ((size_t)c * 8 + nt) * 1024 + (size_t)lane * 8;
    *(uint4*)&wip[base]       = pack8(hi);
    *(uint4*)&wip[base + 512] = pack8(lo);
}

// W'_l = beta_l * conv_w[l] + (1-beta_l) * I ; chunk-major per layer (c=0..3)
__global__ __launch_bounds__(64) void conv_wl(const float* __restrict__ cw,
                                              unsigned short* __restrict__ wlp) {
    int l  = blockIdx.x >> 5;
    int nt = (blockIdx.x >> 2) & 7;
    int c  = blockIdx.x & 3;
    int lane = threadIdx.x;
    float beta = logf(0.5f / (float)(l + 1) + 1.0f);
    int n  = nt * 16 + (lane & 15);
    int kb = c * 32 + (lane >> 4) * 8;
    const float* W = cw + (size_t)l * HID * HID;
    unsigned short hi[8], lo[8];
#pragma unroll
    for (int j = 0; j < 8; j++) {
        int k = kb + j;
        float v = beta * W[(size_t)k * HID + n] + ((k == n) ? (1.0f - beta) : 0.0f);
        hi[j] = f2bf(v);
        lo[j] = f2bf(v - bf2f(hi[j]));
    }
    size_t base = (size_t)l * 32768 + ((size_t)c * 8 + nt) * 1024 + (size_t)lane * 8;
    *(uint4*)&wlp[base]       = pack8(hi);
    *(uint4*)&wlp[base + 512] = pack8(lo);
}

// w_out [128][64] -> B-frags hi/lo per (nt 0..3, c 0..3) (local layout, unstaged)
__global__ __launch_bounds__(64) void conv_wout(const float* __restrict__ w,
                                                unsigned short* __restrict__ wop) {
    int nt = blockIdx.x >> 2;
    int c  = blockIdx.x & 3;
    int lane = threadIdx.x;
    int n  = nt * 16 + (lane & 15);
    int kb = c * 32 + (lane >> 4) * 8;
    unsigned short hi[8], lo[8];
#pragma unroll
    for (int j = 0; j < 8; j++) {
        float v = w[(size_t)(kb + j) * NCLS + n];
        hi[j] = f2bf(v);
        lo[j] = f2bf(v - bf2f(hi[j]));
    }
    size_t base = ((size_t)nt * 4 + c) * 1024 + (size_t)lane * 8;
    *(uint4*)&wop[base]       = pack8(hi);
    *(uint4*)&wop[base + 512] = pack8(lo);
}

// ================= input GEMM: h = x @ w_in + b (LDS-staged weights) =================
__global__ __launch_bounds__(256) void in_gemm_mfma(const float* __restrict__ x,
        const unsigned short* __restrict__ wip, const float* __restrict__ bias,
        unsigned short* __restrict__ hb, unsigned short* __restrict__ h0b) {
    __shared__ unsigned short wlds[8192];      // 16 KB: one K-chunk of B-frags
    __shared__ unsigned short tile[64][136];   // 17 KB output staging
    int tid = threadIdx.x;
    int wave = tid >> 6, lane = tid & 63;
    int t = blockIdx.x * 4 + wave;
    int m = lane & 15, q = lane >> 4;
    int tc = (t < NT) ? t : (NT - 1);          // clamp for address safety

    const uint4* wg = (const uint4*)wip;       // chunk c at uint4 index c*1024
    uint4 pf0 = wg[tid];
    uint4 pf1 = wg[tid + 256];
    uint4 pf2 = wg[tid + 512];
    uint4 pf3 = wg[tid + 768];

    float4v acc[8];
#pragma unroll
    for (int nt = 0; nt < 8; nt++) acc[nt] = (float4v){0.f, 0.f, 0.f, 0.f};
    const float* xr = x + (size_t)(tc * 16 + m) * F_IN + q * 8;
    uint4* wl4 = (uint4*)wlds;

    for (int c = 0; c < 16; c++) {
        wl4[tid] = pf0; wl4[tid + 256] = pf1; wl4[tid + 512] = pf2; wl4[tid + 768] = pf3;
        __syncthreads();
        if (c < 15) {
            const uint4* wn = wg + (size_t)(c + 1) * 1024;
            pf0 = wn[tid]; pf1 = wn[tid + 256]; pf2 = wn[tid + 512]; pf3 = wn[tid + 768];
        }
        float4 x0 = *(const float4*)(xr + c * 32);
        float4 x1 = *(const float4*)(xr + c * 32 + 4);
        short8 ahi, alo;
        split_into(ahi, alo, 0, x0.x); split_into(ahi, alo, 1, x0.y);
        split_into(ahi, alo, 2, x0.z); split_into(ahi, alo, 3, x0.w);
        split_into(ahi, alo, 4, x1.x); split_into(ahi, alo, 5, x1.y);
        split_into(ahi, alo, 6, x1.z); split_into(ahi, alo, 7, x1.w);
#pragma unroll
        for (int nt = 0; nt < 8; nt++) {
            short8 bhi = *(short8*)&wlds[nt * 1024 + lane * 8];
            short8 blo = *(short8*)&wlds[nt * 1024 + 512 + lane * 8];
            acc[nt] = __builtin_amdgcn_mfma_f32_16x16x32_bf16(ahi, bhi, acc[nt], 0, 0, 0);
            acc[nt] = __builtin_amdgcn_mfma_f32_16x16x32_bf16(ahi, blo, acc[nt], 0, 0, 0);
            acc[nt] = __builtin_amdgcn_mfma_f32_16x16x32_bf16(alo, bhi, acc[nt], 0, 0, 0);
        }
        __syncthreads();
    }

    if (t < NT) {
#pragma unroll
        for (int nt = 0; nt < 8; nt++) {
            float bb = bias[nt * 16 + m];
#pragma unroll
            for (int r = 0; r < 4; r++)
                tile[wave * 16 + q * 4 + r][nt * 16 + m] = f2bf(acc[nt][r] + bb);
        }
    }
    __syncthreads();

    int nl = tid >> 2, part = tid & 3;
    int node = blockIdx.x * 64 + nl;
    if (node < N_NODES) {
        uint4* d1 = (uint4*)&hb [(size_t)node * HID + part * 32];
        uint4* d2 = (uint4*)&h0b[(size_t)node * HID + part * 32];
#pragma unroll
        for (int j = 0; j < 4; j++) {
            uint4 u = *(uint4*)&tile[nl][part * 32 + j * 8];
            d1[j] = u; d2[j] = u;
        }
    }
}

// ================= fused SpMM + residual mix + layer GEMM =================
// Block = 64 nodes (4 waves). Phase 1: one node per 16-lane quarter (16 lanes x
// 8 feats = 128); aggregate in registers with 8-deep load batching, residual-
// mix, write MFMA A-frags into swizzled LDS. Phase 2: GEMM h_out = elu(s @ W'_l).
// LAST=1 additionally fuses the out GEMM + log_softmax: elu(h) is re-staged in
// LDS as split hi/lo bf16 rows (XOR-swizzled), multiplied by wop, softmaxed,
// and written straight to the output — no f32 hf round-trip, no extra dispatch.
template <int LAST>
__global__ __launch_bounds__(256, 4) void spmm_gemm(const int* __restrict__ row_ptr,
        const int2* __restrict__ rec, const float* __restrict__ dinv,
        const unsigned short* __restrict__ hin, const unsigned short* __restrict__ h0b,
        const unsigned short* __restrict__ wlp, const unsigned short* __restrict__ wop,
        const float* __restrict__ obias, void* __restrict__ outp) {
    __shared__ __align__(16) unsigned short afr[16384];   // 32 KB A-frags / staging union
    int tid = threadIdx.x;
    int wave = tid >> 6, lane = tid & 63;
    int qu = lane >> 4, fl = lane & 15;
    char* af = (char*)afr;

    // ---- phase 1: aggregation, 4 rounds of (node per quarter) ----
    int base = blockIdx.x * 64 + wave * 16;
#pragma unroll 1
    for (int g = 0; g < 4; ++g) {
        int node = base + g * 4 + qu;
        int nc = (node < N_NODES) ? node : (N_NODES - 1);
        int e0 = row_ptr[nc], e1 = row_ptr[nc + 1];
        // issue self/residual loads early (overlap with gather)
        float dd = dinv[nc];
        uint4 hv = *(const uint4*)(hin + (size_t)nc * HID + fl * 8);
        uint4 zv = *(const uint4*)(h0b + (size_t)nc * HID + fl * 8);
        float a[8] = {0.f, 0.f, 0.f, 0.f, 0.f, 0.f, 0.f, 0.f};
        int e = e0;
        for (; e + 7 < e1; e += 8) {
            int2 r0 = rec[e],     r1 = rec[e + 1], r2 = rec[e + 2], r3 = rec[e + 3];
            int2 r4 = rec[e + 4], r5 = rec[e + 5], r6 = rec[e + 6], r7 = rec[e + 7];
            uint4 u0 = *(const uint4*)(hin + (size_t)r0.x * HID + fl * 8);
            uint4 u1 = *(const uint4*)(hin + (size_t)r1.x * HID + fl * 8);
            uint4 u2 = *(const uint4*)(hin + (size_t)r2.x * HID + fl * 8);
            uint4 u3 = *(const uint4*)(hin + (size_t)r3.x * HID + fl * 8);
            uint4 u4 = *(const uint4*)(hin + (size_t)r4.x * HID + fl * 8);
            uint4 u5 = *(const uint4*)(hin + (size_t)r5.x * HID + fl * 8);
            uint4 u6 = *(const uint4*)(hin + (size_t)r6.x * HID + fl * 8);
            uint4 u7 = *(const uint4*)(hin + (size_t)r7.x * HID + fl * 8);
            bf8_fma(a, u0, __int_as_float(r0.y));
            bf8_fma(a, u1, __int_as_float(r1.y));
            bf8_fma(a, u2, __int_as_float(r2.y));
            bf8_fma(a, u3, __int_as_float(r3.y));
            bf8_fma(a, u4, __int_as_float(r4.y));
            bf8_fma(a, u5, __int_as_float(r5.y));
            bf8_fma(a, u6, __int_as_float(r6.y));
            bf8_fma(a, u7, __int_as_float(r7.y));
        }
        for (; e + 3 < e1; e += 4) {
            int2 r0 = rec[e], r1 = rec[e + 1], r2 = rec[e + 2], r3 = rec[e + 3];
            uint4 u0 = *(const uint4*)(hin + (size_t)r0.x * HID + fl * 8);
            uint4 u1 = *(const uint4*)(hin + (size_t)r1.x * HID + fl * 8);
            uint4 u2 = *(const uint4*)(hin + (size_t)r2.x * HID + fl * 8);
            uint4 u3 = *(const uint4*)(hin + (size_t)r3.x * HID + fl * 8);
            bf8_fma(a, u0, __int_as_float(r0.y));
            bf8_fma(a, u1, __int_as_float(r1.y));
            bf8_fma(a, u2, __int_as_float(r2.y));
            bf8_fma(a, u3, __int_as_float(r3.y));
        }
        for (; e < e1; ++e) {
            int2 r0 = rec[e];
            uint4 u0 = *(const uint4*)(hin + (size_t)r0.x * HID + fl * 8);
            bf8_fma(a, u0, __int_as_float(r0.y));
        }
        // self-loop + initial-residual mix
        float d2 = dd * dd;
        float hvf[8], zvf[8];
        unpack8(hvf, hv);
        unpack8(zvf, zv);
        short8 ohi, olo;
#pragma unroll
        for (int j = 0; j < 8; ++j) {
            float o = 0.9f * (a[j] + d2 * hvf[j]) + 0.1f * zvf[j];
            split_into(ohi, olo, j, o);
        }
        // A-frag layout: byte = wave*8192 + c*2048 + sel*1024 + q*256 + m*16
        // writer: c = fl>>2, q = fl&3, m = row within wave tile
        int mrow = g * 4 + qu;
        int b0 = wave * 8192 + (fl >> 2) * 2048 + (fl & 3) * 256 + mrow * 16;
        *(short8*)(af + SWZB(b0)) = ohi;
        *(short8*)(af + SWZB(b0 + 1024)) = olo;
    }
    __syncthreads();   // all A-frags visible

    // ---- phase 2: GEMM, A from LDS, B from global ----
    float4v acc[8];
#pragma unroll
    for (int nt = 0; nt < 8; ++nt) acc[nt] = (float4v){0.f, 0.f, 0.f, 0.f};
    const short8* wp8 = (const short8*)wlp;
#pragma unroll
    for (int c = 0; c < 4; ++c) {
        int rb = wave * 8192 + c * 2048 + lane * 16;
        short8 ahi = *(const short8*)(af + SWZB(rb));
        short8 alo = *(const short8*)(af + SWZB(rb + 1024));
#pragma unroll
        for (int nt = 0; nt < 8; ++nt) {
            short8 bhi = wp8[(size_t)(c * 8 + nt) * 128 + lane];
            short8 blo = wp8[(size_t)(c * 8 + nt) * 128 + 64 + lane];
            acc[nt] = __builtin_amdgcn_mfma_f32_16x16x32_bf16(ahi, bhi, acc[nt], 0, 0, 0);
            acc[nt] = __builtin_amdgcn_mfma_f32_16x16x32_bf16(ahi, blo, acc[nt], 0, 0, 0);
            acc[nt] = __builtin_amdgcn_mfma_f32_16x16x32_bf16(alo, bhi, acc[nt], 0, 0, 0);
        }
    }

    if (LAST) {
        // ---- phase 3: fused out GEMM + log_softmax ----
        int t = blockIdx.x * 4 + wave;
        __syncthreads();   // A-frag reads done; reuse afr for hi/lo row planes
        char* wb = af + wave * 8192;   // hi plane [0,4096), lo plane [4096,8192)
        if (t < NT) {
#pragma unroll
            for (int nt = 0; nt < 8; ++nt) {
#pragma unroll
                for (int r = 0; r < 4; ++r) {
                    float v = acc[nt][r];
                    v = (v > 0.f) ? v : (expf(v) - 1.0f);
                    unsigned short h = f2bf(v);
                    unsigned short l = f2bf(v - bf2f(h));
                    int b = (qu * 4 + r) * 256 + (nt * 16 + fl) * 2;
                    *(unsigned short*)(wb + SWZC(b)) = h;
                    *(unsigned short*)(wb + 4096 + SWZC(b)) = l;
                }
            }
        }
        __syncthreads();
        if (t < NT) {
            float4v oc[4];
#pragma unroll
            for (int nt = 0; nt < 4; ++nt) oc[nt] = (float4v){0.f, 0.f, 0.f, 0.f};
            const short8* wq = (const short8*)wop;
#pragma unroll
            for (int c = 0; c < 4; ++c) {
                int rb = fl * 256 + (c * 32 + qu * 8) * 2;
                short8 ahi = *(const short8*)(wb + SWZC(rb));
                short8 alo = *(const short8*)(wb + 4096 + SWZC(rb));
#pragma unroll
                for (int nt = 0; nt < 4; ++nt) {
                    short8 bhi = wq[(size_t)(nt * 4 + c) * 128 + lane];
                    short8 blo = wq[(size_t)(nt * 4 + c) * 128 + 64 + lane];
                    oc[nt] = __builtin_amdgcn_mfma_f32_16x16x32_bf16(ahi, bhi, oc[nt], 0, 0, 0);
                    oc[nt] = __builtin_amdgcn_mfma_f32_16x16x32_bf16(ahi, blo, oc[nt], 0, 0, 0);
                    oc[nt] = __builtin_amdgcn_mfma_f32_16x16x32_bf16(alo, bhi, oc[nt], 0, 0, 0);
                }
            }
            float* out = (float*)outp;
            float bn[4];
#pragma unroll
            for (int nt = 0; nt < 4; ++nt) bn[nt] = obias[nt * 16 + fl];
#pragma unroll
            for (int r = 0; r < 4; ++r) {
                float v0 = oc[0][r] + bn[0], v1 = oc[1][r] + bn[1];
                float v2 = oc[2][r] + bn[2], v3 = oc[3][r] + bn[3];
                float mx = fmaxf(fmaxf(v0, v1), fmaxf(v2, v3));
#pragma unroll
                for (int msk = 1; msk < 16; msk <<= 1) mx = fmaxf(mx, __shfl_xor(mx, msk));
                float ssum = expf(v0 - mx) + expf(v1 - mx) + expf(v2 - mx) + expf(v3 - mx);
#pragma unroll
                for (int msk = 1; msk < 16; msk <<= 1) ssum += __shfl_xor(ssum, msk);
                float lg = mx + logf(ssum);
                size_t ob = (size_t)(t * 16 + qu * 4 + r) * NCLS + fl;
                out[ob]      = v0 - lg;
                out[ob + 16] = v1 - lg;
                out[ob + 32] = v2 - lg;
                out[ob + 48] = v3 - lg;
            }
        }
    } else {
        __syncthreads();   // A-frag reads done; reuse afr as output tile
        unsigned short (*tile)[136] = (unsigned short (*)[136])afr;
#pragma unroll
        for (int nt = 0; nt < 8; ++nt) {
#pragma unroll
            for (int r = 0; r < 4; ++r) {
                float v = acc[nt][r];
                v = (v > 0.f) ? v : (expf(v) - 1.0f);
                tile[wave * 16 + qu * 4 + r][nt * 16 + fl] = f2bf(v);
            }
        }
        __syncthreads();
        unsigned short* hout = (unsigned short*)outp;
        int nl = tid >> 2, part = tid & 3;
        int node = blockIdx.x * 64 + nl;
        if (node < N_NODES) {
            uint4* d1 = (uint4*)&hout[(size_t)node * HID + part * 32];
#pragma unroll
            for (int j = 0; j < 4; ++j) d1[j] = *(uint4*)&tile[nl][part * 32 + j * 8];
        }
    }
}

// ================= launch =================

extern "C" void kernel_launch(void* const* d_in, const int* in_sizes, int n_in,
                              void* d_out, int out_size, void* d_ws, size_t ws_size,
                              hipStream_t stream) {
    const float* x      = (const float*)d_in[0];
    const int*   ei     = (const int*)  d_in[1];
    const float* w_in   = (const float*)d_in[2];
    const float* b_in   = (const float*)d_in[3];
    const float* conv_w = (const float*)d_in[4];
    const float* w_out  = (const float*)d_in[5];
    const float* b_out  = (const float*)d_in[6];
    float* out = (float*)d_out;

    const int* srcI = ei;
    const int* dstI = ei + N_EDGES;

    char* ws = (char*)d_ws;
    float* dinv    = (float*)(ws + 0x000000);
    int*   cnt     = (int*)  (ws + 0x080000);
    int*   partial = (int*)  (ws + 0x100000);
    int*   bsum    = (int*)  (ws + 0x180000);
    int*   row_ptr = (int*)  (ws + 0x190000);
    int*   cursor  = (int*)  (ws + 0x200000);
    int2*  rec     = (int2*) (ws + 0x280000);                  // 12.8 MB
    unsigned short* wip = (unsigned short*)(ws + 0xF00000);    // 256 KB
    unsigned short* wlp = (unsigned short*)(ws + 0xF40000);    // 512 KB
    unsigned short* wop = (unsigned short*)(ws + 0xFC0000);    // 32 KB
    unsigned short* hb  = (unsigned short*)(ws + 0x1000000);   // 25.6 MB
    unsigned short* h0b = hb + (size_t)N_NODES * HID;          // 25.6 MB
    unsigned short* hb2 = h0b + (size_t)N_NODES * HID;         // 25.6 MB (ping-pong)

    int gN = (N_NODES + 255) / 256;
    int gE = (N_EDGES + 255) / 256;
    int gT = (NT + 3) / 4;                                     // 1563 (= 64-node blocks)

    cnt_init<<<gN, 256, 0, stream>>>(cnt);
    cnt_count<<<gE, 256, 0, stream>>>(dstI, cnt);
    make_dinv<<<gN, 256, 0, stream>>>(cnt, dinv);
    scan_block<<<NSCANB, 256, 0, stream>>>(cnt, partial, bsum);
    scan_b2<<<1, 256, 0, stream>>>(bsum);
    finalize_rowptr<<<NSCANB, 256, 0, stream>>>(cnt, partial, bsum, row_ptr, cursor);
    scatter_edges<<<gE, 256, 0, stream>>>(srcI, dstI, dinv, cursor, rec);

    conv_win<<<128, 64, 0, stream>>>(w_in, wip);
    conv_wl<<<256, 64, 0, stream>>>(conv_w, wlp);
    conv_wout<<<16, 64, 0, stream>>>(w_out, wop);

    in_gemm_mfma<<<gT, 256, 0, stream>>>(x, wip, b_in, hb, h0b);

    unsigned short* cur = hb;
    unsigned short* nxt = hb2;
    for (int l = 0; l < NLAYERS; l++) {
        const unsigned short* wl = wlp + (size_t)l * 32768;
        if (l < NLAYERS - 1) {
            spmm_gemm<0><<<gT, 256, 0, stream>>>(row_ptr, rec, dinv, cur, h0b, wl,
                                                 nullptr, nullptr, nxt);
            unsigned short* t = cur; cur = nxt; nxt = t;
        } else {
            spmm_gemm<1><<<gT, 256, 0, stream>>>(row_ptr, rec, dinv, cur, h0b, wl,
                                                 wop, b_out, out);
        }
    }
}